// Round 7
// baseline (217.296 us; speedup 1.0000x reference)
//
#include <hip/hip_runtime.h>
#include <hip/hip_bf16.h>

// Problem constants: B=2, S=2048, D=1024, H=16, DH=64
#define SS 2048
#define DD 1024
#define GK 1024   // GEMM K = D
#define GM 4096   // GEMM M = B*S

// log2(e)/8 : folded into Q projection so attention softmax is exp2(s)
#define QSCALE 0.18033688011112042f

typedef __attribute__((ext_vector_type(8))) short short8;    // 8 bf16 = 4 VGPRs
typedef __attribute__((ext_vector_type(16))) float f32x16;   // 32x32 MFMA C/D
typedef __attribute__((ext_vector_type(2))) float f32x2;
typedef __attribute__((ext_vector_type(4))) int i32x4;

__device__ __forceinline__ short f2bf(float f) {
  union { __hip_bfloat16 h; short s; } u;
  u.h = __float2bfloat16(f);
  return u.s;
}

__device__ __forceinline__ short2 pk2bf(float a, float b) {
  union { __hip_bfloat162 h; short2 s; } u;
  u.h = __float22bfloat162_rn(float2{a, b});
  return u.s;
}

__device__ __forceinline__ int pk2bf_i(float a, float b) {
  union { __hip_bfloat162 h; int i; } u;
  u.h = __float22bfloat162_rn(float2{a, b});
  return u.i;
}

// async global->LDS, 16B per lane; LDS dest = wave-uniform base + lane*16
__device__ __forceinline__ void gld16(const void* g, void* l) {
  __builtin_amdgcn_global_load_lds(
      (const __attribute__((address_space(1))) void*)g,
      (__attribute__((address_space(3))) void*)l, 16, 0, 0);
}

// Tile swizzle: stored chunk c of row r holds source chunk c^(r&7)^((r>>3)&3).
__device__ __forceinline__ int swz(int row, int col) {
  return (col ^ (row & 7) ^ ((row >> 3) & 3)) << 3;
}

// ---------------------------------------------------------------------------
// fp32 -> bf16 convert, weights only (q/k/v conversion fused into qkv_gemm)
// ---------------------------------------------------------------------------
struct CvtArgs {
  const float* s[4];
  short* d[4];
};

__global__ __launch_bounds__(256) void cvt_all(CvtArgs a) {
  const int y = blockIdx.y;
  const int i = blockIdx.x * 256 + threadIdx.x;  // 131072 chunks of 8
  const float4* sp = (const float4*)a.s[y];
  float4 u = sp[2 * i], v = sp[2 * i + 1];
  short8 o;
  short2 p0 = pk2bf(u.x, u.y), p1 = pk2bf(u.z, u.w);
  short2 p2 = pk2bf(v.x, v.y), p3 = pk2bf(v.z, v.w);
  o[0] = p0.x; o[1] = p0.y; o[2] = p1.x; o[3] = p1.y;
  o[4] = p2.x; o[5] = p2.y; o[6] = p3.x; o[7] = p3.y;
  ((short8*)a.d[y])[i] = o;
}

// ---------------------------------------------------------------------------
// Fused QKV projection GEMM. A = x (fp32 -> bf16 during staging, loads
// pipelined one k-step ahead), B = W (bf16, async gld16). grid = 768
// blocks, 3 blocks/CU, XCD-remapped. V^T epilogue via LDS transpose.
// ---------------------------------------------------------------------------
struct QkvArgs {
  const float* A[3];   // fp32 inputs q,k,v
  const short* W[3];
  const float* b[3];
  short* out[3];
};

__global__ __launch_bounds__(256, 3) void qkv_gemm(QkvArgs args) {
  // bijective flat-id remap: xcd = f&7 (hardware round-robin assumption)
  const int f = blockIdx.x + 32 * (blockIdx.y + 8 * blockIdx.z);
  const int xcd = f & 7, slot = f >> 3;   // slot in [0,96)
  const int z = slot >> 5;                // which projection (q/k/v)
  const int rem = slot & 31;
  const int m0 = (xcd * 4 + (rem & 3)) * 128;  // s
  const int n0 = (rem >> 2) * 128;             // feat

  const float* __restrict__ A = args.A[z];
  const short* __restrict__ W = args.W[z];
  const float* __restrict__ bias = args.b[z];
  short* __restrict__ Cout = args.out[z];

  const int tid = threadIdx.x;
  const int wave = tid >> 6, lane = tid & 63;
  const int l32 = lane & 31, half = lane >> 5;
  const int wrow = (wave >> 1) * 64;
  const int wcol = (wave & 1) * 64;
  const int lxor = (l32 & 7) ^ ((l32 >> 3) & 3);

  __shared__ short smem[16384];              // 32 KB: Am | Wm, reused as TT
  short (*Am)[64] = (short(*)[64])smem;          // [128][64] swizzled
  short (*Wm)[64] = (short(*)[64])(smem + 8192); // [128][64] swizzled

  f32x16 acc[2][2];
#pragma unroll
  for (int mb = 0; mb < 2; mb++)
#pragma unroll
    for (int nb = 0; nb < 2; nb++) acc[mb][nb] = (f32x16)0.f;

  // Per-thread A-staging geometry (constant across k): 4 chunks
  int arow[4], acolsw[4];
#pragma unroll
  for (int i = 0; i < 4; i++) {
    int f2 = wave * 256 + i * 64 + lane;
    arow[i] = f2 >> 3;
    acolsw[i] = swz(arow[i], f2 & 7);
  }

  // Prologue: load A chunks for k0 = 0
  float4 au[4], av[4];
#pragma unroll
  for (int i = 0; i < 4; i++) {
    const float* src = A + (size_t)(m0 + arow[i]) * GK + acolsw[i];
    au[i] = *(const float4*)src;
    av[i] = *(const float4*)(src + 4);
  }

  for (int k0 = 0; k0 < GK; k0 += 64) {
    __syncthreads();
#pragma unroll
    for (int i = 0; i < 4; i++) {
      int f2 = wave * 256 + i * 64 + lane;
      // A: convert the prefetched regs -> LDS (RN, same as old cvt pass)
      short8 o;
      short2 p0 = pk2bf(au[i].x, au[i].y), p1 = pk2bf(au[i].z, au[i].w);
      short2 p2 = pk2bf(av[i].x, av[i].y), p3 = pk2bf(av[i].z, av[i].w);
      o[0] = p0.x; o[1] = p0.y; o[2] = p1.x; o[3] = p1.y;
      o[4] = p2.x; o[5] = p2.y; o[6] = p3.x; o[7] = p3.y;
      *(short8*)((short*)Am + (size_t)f2 * 8) = o;
      // W: bf16 async global->LDS
      gld16(W + (size_t)(n0 + arow[i]) * GK + k0 + acolsw[i],
            (short*)Wm + (size_t)(wave * 256 + i * 64) * 8);
    }
    // Issue next k-step's A loads; in flight across the compute phase.
    if (k0 + 64 < GK) {
#pragma unroll
      for (int i = 0; i < 4; i++) {
        const float* src =
            A + (size_t)(m0 + arow[i]) * GK + (k0 + 64) + acolsw[i];
        au[i] = *(const float4*)src;
        av[i] = *(const float4*)(src + 4);
      }
    }
    __syncthreads();
#pragma unroll
    for (int c = 0; c < 4; c++) {
      const int sw = ((2 * c + half) ^ lxor) << 3;
      short8 af[2], bf[2];
#pragma unroll
      for (int mb = 0; mb < 2; mb++) {
        af[mb] = *(const short8*)(&Am[wrow + mb * 32 + l32][0] + sw);
        bf[mb] = *(const short8*)(&Wm[wcol + mb * 32 + l32][0] + sw);
      }
#pragma unroll
      for (int mb = 0; mb < 2; mb++)
#pragma unroll
        for (int nb = 0; nb < 2; nb++)
          acc[mb][nb] = __builtin_amdgcn_mfma_f32_32x32x16_bf16(
              af[mb], bf[nb], acc[mb][nb], 0, 0, 0);
    }
  }

  const int bb = m0 >> 11;

  if (z == 2) {
    // --- V^T epilogue: transpose via LDS, coalesced stores ---
    __syncthreads();  // all K-loop LDS reads done before overwrite
    short* TT = smem; // [128 feat][16 chunks of 8 s], chunk-XOR swizzled
#pragma unroll
    for (int nb = 0; nb < 2; nb++) {
      const int fl = wcol + nb * 32 + l32;   // feat_local 0..127
      const float bv = bias[n0 + fl];
#pragma unroll
      for (int mb = 0; mb < 2; mb++)
#pragma unroll
        for (int g = 0; g < 4; g++) {
          const int cs = (wrow >> 3) + mb * 4 + g;            // 0..15
          const int csw = cs ^ (fl & 7) ^ ((fl >> 3) & 3);
          short2 o0 = pk2bf(acc[mb][nb][4 * g + 0] + bv,
                            acc[mb][nb][4 * g + 1] + bv);
          short2 o1 = pk2bf(acc[mb][nb][4 * g + 2] + bv,
                            acc[mb][nb][4 * g + 3] + bv);
          short4 o4 = {o0.x, o0.y, o1.x, o1.y};
          *(short4*)&TT[fl * 128 + csw * 8 + 4 * half] = o4;
        }
    }
    __syncthreads();
    {
      const int fl = tid >> 1;                       // feat row 0..127
      const int h = (n0 + fl) >> 6, d = (n0 + fl) & 63;
      short* dst = Cout + ((size_t)(bb * 16 + h) * 64 + d) * 2048 +
                   (m0 & 2047) + (tid & 1) * 64;
#pragma unroll
      for (int j = 0; j < 8; j++) {
        const int c8 = (tid & 1) * 8 + j;
        const int csw = c8 ^ (fl & 7) ^ ((fl >> 3) & 3);
        *(short8*)(dst + j * 8) = *(const short8*)&TT[fl * 128 + csw * 8];
      }
    }
    return;
  }

  // --- q/k epilogue: n(lane)=feat, m(regs)=s. Coalesced along feat. ---
  const float sc = (z == 0) ? QSCALE : 1.0f;
#pragma unroll
  for (int nb = 0; nb < 2; nb++) {
    const int n = n0 + wcol + nb * 32 + l32;
    const float bv = bias[n];
    const int h = n >> 6, d = n & 63;
#pragma unroll
    for (int mb = 0; mb < 2; mb++) {
      const int mbase = m0 + wrow + mb * 32 + 4 * half;
#pragma unroll
      for (int g = 0; g < 4; g++)
#pragma unroll
        for (int r = 0; r < 4; r++) {
          const int s = (mbase + g * 8 + r) & 2047;
          Cout[((size_t)(bb * 16 + h) * 2048 + s) * 64 + d] =
              f2bf((acc[mb][nb][4 * g + r] + bv) * sc);
        }
    }
  }
}

// ---------------------------------------------------------------------------
// O-projection GEMM, BK=128: 16 MFMA/wave/iter, 16 barriers. LDS 48 KB,
// grid (32,16) = 512 = 2 blocks/CU. fp32 out, coalesced along feat.
// XCD remap: each XCD owns 4 m-panels x all 16 n-tiles: A 1MB + W 2MB.
// ---------------------------------------------------------------------------
__global__ __launch_bounds__(256) void gemm_o(
    const short* __restrict__ A, const short* __restrict__ W,
    const float* __restrict__ bias, float* __restrict__ Cout) {
  const int f = blockIdx.x + 32 * blockIdx.y;
  const int xcd = f & 7, slot = f >> 3;        // slot in [0,64)
  const int m0 = (xcd * 4 + (slot & 3)) * 128; // s
  const int n0 = (slot >> 2) * 64;             // feat

  const int tid = threadIdx.x;
  const int wave = tid >> 6, lane = tid & 63;
  const int l32 = lane & 31, half = lane >> 5;
  const int lxor = (l32 & 7) ^ ((l32 >> 3) & 3);

  __shared__ short Am[128][128];  // [s][k], swizzled (32 KB)
  __shared__ short Wm[64][128];   // [feat][k], swizzled (16 KB)

  f32x16 acc[2];
  acc[0] = (f32x16)0.f;
  acc[1] = (f32x16)0.f;

  for (int k0 = 0; k0 < GK; k0 += 128) {
    __syncthreads();
    // A: 128 rows x 16 chunks = 2048 chunks -> 8 per thread
#pragma unroll
    for (int i = 0; i < 8; i++) {
      int f2 = tid + i * 256;
      int row = f2 >> 4, col = f2 & 15;
      gld16(A + (size_t)(m0 + row) * GK + k0 + swz(row, col),
            (short*)Am + (size_t)(wave * 64 + i * 256) * 8);
    }
    // W: 64 rows x 16 chunks = 1024 chunks -> 4 per thread
#pragma unroll
    for (int i = 0; i < 4; i++) {
      int f2 = tid + i * 256;
      int row = f2 >> 4, col = f2 & 15;
      gld16(W + (size_t)(n0 + row) * GK + k0 + swz(row, col),
            (short*)Wm + (size_t)(wave * 64 + i * 256) * 8);
    }
    __syncthreads();
#pragma unroll
    for (int c = 0; c < 8; c++) {
      const int sw = ((2 * c + half) ^ lxor) << 3;
      short8 af = *(const short8*)(&Am[wave * 32 + l32][0] + sw);
      short8 bf[2];
#pragma unroll
      for (int nb = 0; nb < 2; nb++)
        bf[nb] = *(const short8*)(&Wm[nb * 32 + l32][0] + sw);
#pragma unroll
      for (int nb = 0; nb < 2; nb++)
        acc[nb] = __builtin_amdgcn_mfma_f32_32x32x16_bf16(
            af, bf[nb], acc[nb], 0, 0, 0);
    }
  }

  // n(lane)=feat -> coalesced scalar stores
#pragma unroll
  for (int nb = 0; nb < 2; nb++) {
    const int n = n0 + nb * 32 + l32;
    const float bv = bias[n];
    const int mbase = m0 + wave * 32 + 4 * half;
#pragma unroll
    for (int g = 0; g < 4; g++)
#pragma unroll
      for (int r = 0; r < 4; r++)
        Cout[(size_t)(mbase + g * 8 + r) * DD + n] = acc[nb][4 * g + r] + bv;
  }
}

// ---------------------------------------------------------------------------
// Flash attention, round-7: register-neutral intra-phase overlap.
// Round-3's overlap idea was right but its vf[2][4] preload (+32 VGPR)
// blew the exact 128-reg/lane budget (64 VGPR + 64 AGPR) -> scratch spill.
// This version keeps round-2's inline V reads (no preload) and only
// reorders: QK -> exp2(s0)+pack(p0,p1) -> PV c=0,1 -> exp2(s1)+pack(p2,p3)
// -> PV c=2,3 -> l-sum (runs under PV c=2,3's matrix-pipe shadow).
// Peak register pressure identical to round-2. Tripwire: WRITE_SIZE must
// stay 15360 KB (scratch spill would raise it).
// ---------------------------------------------------------------------------
__global__ __launch_bounds__(512, 4) void flash_mfma(
    const short* __restrict__ qh, const short* __restrict__ kh,
    const short* __restrict__ vt, short* __restrict__ ao) {
  // bijective remap: hardware flat id -> (bh, q-tile), 4 bh per XCD
  const int n = blockIdx.x + 16 * blockIdx.y;
  const int xcd = n & 7, slot = n >> 3;   // slot in [0,64)
  const int bh = xcd * 4 + (slot >> 4);
  const int q0 = (slot & 15) * 128;

  const int tid = threadIdx.x;
  const int w = tid >> 6, lane = tid & 63;
  const int grp = w >> 2;   // 0: even kt tiles, 1: odd kt tiles
  const int qw = w & 3;     // q sub-block (32 rows)
  const int l32 = lane & 31, half = lane >> 5;
  const int lxor = (l32 & 7) ^ ((l32 >> 3) & 3);

  __shared__ short Ks[4][64][64];   // 4 bufs x [kk][d], swizzled (32 KB)
  __shared__ short Vs[4][64][64];   // 4 bufs x [d][kk], swizzled (32 KB)

  // Q B-fragments from global: q = l32, chunk c: d = c*16 + half*8
  short8 qf[4];
#pragma unroll
  for (int c = 0; c < 4; c++)
    qf[c] = *(const short8*)(
        qh + ((size_t)bh * SS + q0 + qw * 32 + l32) * 64 + c * 16 + half * 8);

  f32x16 o[2];
  o[0] = (f32x16)0.f;
  o[1] = (f32x16)0.f;
  float l_part = 0.f;

  // Staging: thread owns chunk tid of each 64x64 tile (8 waves cover it).
  const int row = tid >> 3, col = tid & 7;
  const short* kb = kh + ((size_t)bh * SS + row) * 64 + swz(row, col);
  const short* vb = vt + ((size_t)bh * 64 + row) * SS + swz(row, col);
  short* kd = (short*)Ks + w * 512;   // wave-uniform LDS dest (+ buf*4096)
  short* vd = (short*)Vs + w * 512;

  // Prologue: tiles 0,1 -> bufs 0,1
  gld16(kb, kd);
  gld16(kb + 4096, kd + 4096);
  gld16(vb, vd);
  gld16(vb + 64, vd + 4096);
  const short* kp = kb + 8192;  // tile 2 (advances 2 tiles/phase)
  const short* vp = vb + 128;
  __syncthreads();

  auto phase = [&](const int bufbase, const bool pf) {
    if (pf) {  // prefetch next tile pair into the other buffer pair
      const int pb = bufbase ^ 2;
      gld16(kp, kd + pb * 4096);
      gld16(kp + 4096, kd + (pb + 1) * 4096);
      gld16(vp, vd + pb * 4096);
      gld16(vp + 64, vd + (pb + 1) * 4096);
      kp += 8192;
      vp += 128;
    }
    const int b = bufbase + grp;

    // S^T = K · Q^T : m = kk (2 blocks), n = q
    f32x16 s[2];
    s[0] = (f32x16)0.f;
    s[1] = (f32x16)0.f;
    __builtin_amdgcn_s_setprio(1);
#pragma unroll
    for (int c = 0; c < 4; c++) {
      const int sw = ((2 * c + half) ^ lxor) << 3;
      short8 kf[2];
#pragma unroll
      for (int mb = 0; mb < 2; mb++)
        kf[mb] = *(const short8*)(&Ks[b][mb * 32 + l32][0] + sw);
#pragma unroll
      for (int mb = 0; mb < 2; mb++)
        s[mb] = __builtin_amdgcn_mfma_f32_32x32x16_bf16(
            kf[mb], qf[c], s[mb], 0, 0, 0);
    }
    __builtin_amdgcn_s_setprio(0);

    short8 pfrag[4];

    // exp2 + pack for s[0] -> pfrag[0,1]
#pragma unroll
    for (int r = 0; r < 16; r++)
      s[0][r] = __builtin_amdgcn_exp2f(s[0][r]);
    {
      int u0[4], u1[4];
#pragma unroll
      for (int g = 0; g < 4; g++) {
        u0[g] = pk2bf_i(s[0][4 * g + 0], s[0][4 * g + 1]);
        u1[g] = pk2bf_i(s[0][4 * g + 2], s[0][4 * g + 3]);
      }
#pragma unroll
      for (int cc = 0; cc < 2; cc++) {
        auto r0 = __builtin_amdgcn_permlane32_swap(u0[2 * cc], u0[2 * cc + 1],
                                                   false, false);
        auto r1 = __builtin_amdgcn_permlane32_swap(u1[2 * cc], u1[2 * cc + 1],
                                                   false, false);
        union { i32x4 i; short8 s8; } pu;
        pu.i = i32x4{(int)r0[0], (int)r1[0], (int)r0[1], (int)r1[1]};
        pfrag[cc] = pu.s8;
      }
    }

    // PV c=0,1 (inline V reads; independent of s[1] -> exp2(s[1]) overlaps)
    __builtin_amdgcn_s_setprio(1);
#pragma unroll
    for (int c = 0; c < 2; c++) {
      const int sw = ((2 * c + half) ^ lxor) << 3;
      short8 vf[2];
#pragma unroll
      for (int mb = 0; mb < 2; mb++)
        vf[mb] = *(const short8*)(&Vs[b][mb * 32 + l32][0] + sw);
#pragma unroll
      for (int mb = 0; mb < 2; mb++)
        o[mb] = __builtin_amdgcn_mfma_f32_32x32x16_bf16(
            vf[mb], pfrag[c], o[mb], 0, 0, 0);
    }
    __builtin_amdgcn_s_setprio(0);

    // exp2 + pack for s[1] -> pfrag[2,3] (under PV c=0,1's shadow)
#pragma unroll
    for (int r = 0; r < 16; r++)
      s[1][r] = __builtin_amdgcn_exp2f(s[1][r]);
    {
      int u0[4], u1[4];
#pragma unroll
      for (int g = 0; g < 4; g++) {
        u0[g] = pk2bf_i(s[1][4 * g + 0], s[1][4 * g + 1]);
        u1[g] = pk2bf_i(s[1][4 * g + 2], s[1][4 * g + 3]);
      }
#pragma unroll
      for (int cc = 0; cc < 2; cc++) {
        auto r0 = __builtin_amdgcn_permlane32_swap(u0[2 * cc], u0[2 * cc + 1],
                                                   false, false);
        auto r1 = __builtin_amdgcn_permlane32_swap(u1[2 * cc], u1[2 * cc + 1],
                                                   false, false);
        union { i32x4 i; short8 s8; } pu;
        pu.i = i32x4{(int)r0[0], (int)r1[0], (int)r0[1], (int)r1[1]};
        pfrag[2 + cc] = pu.s8;
      }
    }

    // PV c=2,3
    __builtin_amdgcn_s_setprio(1);
#pragma unroll
    for (int c = 2; c < 4; c++) {
      const int sw = ((2 * c + half) ^ lxor) << 3;
      short8 vf[2];
#pragma unroll
      for (int mb = 0; mb < 2; mb++)
        vf[mb] = *(const short8*)(&Vs[b][mb * 32 + l32][0] + sw);
#pragma unroll
      for (int mb = 0; mb < 2; mb++)
        o[mb] = __builtin_amdgcn_mfma_f32_32x32x16_bf16(
            vf[mb], pfrag[c], o[mb], 0, 0, 0);
    }
    __builtin_amdgcn_s_setprio(0);

    // per-lane partial l (VALU; runs under PV c=2,3's matrix-pipe shadow)
    {
      f32x2 t[8];
#pragma unroll
      for (int r = 0; r < 8; r++)
        t[r] = f32x2{s[0][2 * r], s[0][2 * r + 1]} +
               f32x2{s[1][2 * r], s[1][2 * r + 1]};
#pragma unroll
      for (int st = 4; st > 0; st >>= 1)
#pragma unroll
        for (int r = 0; r < st; r++) t[r] += t[r + st];
      l_part += t[0].x + t[0].y;
    }

    __syncthreads();  // drains prefetch + guards buffer reuse
  };

#pragma unroll 1
  for (int p2 = 0; p2 < 8; p2++) {
    phase(0, true);       // tiles 4*p2, 4*p2+1 (bufs 0,1); stage bufs 2,3
    phase(2, p2 != 7);    // tiles 4*p2+2,+3  (bufs 2,3); stage bufs 0,1
  }

  // Epilogue: merge group-1 partials into group-0 via LDS, then store.
  float* fb = (float*)Ks;  // 32*256 f32 = 32 KB
  float* lb = (float*)Vs;
  if (grp == 1) {
#pragma unroll
    for (int mb = 0; mb < 2; mb++)
#pragma unroll
      for (int r = 0; r < 16; r++)
        fb[(mb * 16 + r) * 256 + qw * 64 + lane] = o[mb][r];
    lb[qw * 64 + lane] = l_part;
  }
  __syncthreads();
  if (grp == 0) {
#pragma unroll
    for (int mb = 0; mb < 2; mb++)
#pragma unroll
      for (int r = 0; r < 16; r++)
        o[mb][r] += fb[(mb * 16 + r) * 256 + qw * 64 + lane];
    l_part += lb[qw * 64 + lane];

    const float l_tot = l_part + __shfl_xor(l_part, 32);
    const float inv = 1.0f / l_tot;
    const int b_ = bh >> 4, h = bh & 15;
    const int q = q0 + qw * 32 + l32;
#pragma unroll
    for (int mb = 0; mb < 2; mb++)
#pragma unroll
      for (int g = 0; g < 4; g++) {
        const int d = mb * 32 + g * 8 + half * 4;
        short2 o0 = pk2bf(o[mb][4 * g + 0] * inv, o[mb][4 * g + 1] * inv);
        short2 o1 = pk2bf(o[mb][4 * g + 2] * inv, o[mb][4 * g + 3] * inv);
        short4 ok = {o0.x, o0.y, o1.x, o1.y};
        *(short4*)&ao[((size_t)b_ * SS + q) * DD + h * 64 + d] = ok;
      }
  }
}

// ---------------------------------------------------------------------------
extern "C" void kernel_launch(void* const* d_in, const int* in_sizes, int n_in,
                              void* d_out, int out_size, void* d_ws,
                              size_t ws_size, hipStream_t stream) {
  const float* q = (const float*)d_in[0];
  const float* k = (const float*)d_in[1];
  const float* v = (const float*)d_in[2];
  const float* Wq = (const float*)d_in[3];
  const float* bq = (const float*)d_in[4];
  const float* Wk = (const float*)d_in[5];
  const float* bk = (const float*)d_in[6];
  const float* Wv = (const float*)d_in[7];
  const float* bv = (const float*)d_in[8];
  const float* Wo = (const float*)d_in[9];
  const float* bo = (const float*)d_in[10];
  float* out = (float*)d_out;

  const size_t MEG = 1024 * 1024;
  short* wsb = (short*)d_ws;
  short* Wqb = wsb + 0 * MEG;
  short* Wkb = wsb + 1 * MEG;
  short* Wvb = wsb + 2 * MEG;
  short* Wob = wsb + 3 * MEG;
  short* qhp = wsb + 16 * MEG;  // [B*H][S][DH] (pre-scaled by log2e/8)
  short* khp = wsb + 20 * MEG;  // [B*H][S][DH]
  short* vtp = wsb + 24 * MEG;  // [B*H][DH][S]
  short* aop = wsb + 28 * MEG;  // [B,S,D]

  CvtArgs ca;
  ca.s[0] = Wq; ca.d[0] = Wqb;
  ca.s[1] = Wk; ca.d[1] = Wkb;
  ca.s[2] = Wv; ca.d[2] = Wvb;
  ca.s[3] = Wo; ca.d[3] = Wob;
  cvt_all<<<dim3(512, 4), 256, 0, stream>>>(ca);

  QkvArgs qa;
  qa.A[0] = q; qa.W[0] = Wqb; qa.b[0] = bq; qa.out[0] = qhp;
  qa.A[1] = k; qa.W[1] = Wkb; qa.b[1] = bk; qa.out[1] = khp;
  qa.A[2] = v; qa.W[2] = Wvb; qa.b[2] = bv; qa.out[2] = vtp;
  qkv_gemm<<<dim3(GM / 128, DD / 128, 3), 256, 0, stream>>>(qa);

  flash_mfma<<<dim3(SS / 128, 32), 512, 0, stream>>>(qhp, khp, vtp, aop);

  gemm_o<<<dim3(GM / 128, DD / 64), 256, 0, stream>>>(aop, Wob, bo, out);
}

// Round 9
// 211.326 us; speedup vs baseline: 1.0282x; 1.0282x over previous
//
#include <hip/hip_runtime.h>
#include <hip/hip_bf16.h>

// Problem constants: B=2, S=2048, D=1024, H=16, DH=64
#define SS 2048
#define DD 1024
#define GK 1024   // GEMM K = D
#define GM 4096   // GEMM M = B*S

// log2(e)/8 : folded into Q projection so attention softmax is exp2(s)
#define QSCALE 0.18033688011112042f

typedef __attribute__((ext_vector_type(8))) short short8;    // 8 bf16 = 4 VGPRs
typedef __attribute__((ext_vector_type(16))) float f32x16;   // 32x32 MFMA C/D
typedef __attribute__((ext_vector_type(2))) float f32x2;
typedef __attribute__((ext_vector_type(4))) int i32x4;

__device__ __forceinline__ short f2bf(float f) {
  union { __hip_bfloat16 h; short s; } u;
  u.h = __float2bfloat16(f);
  return u.s;
}

__device__ __forceinline__ short2 pk2bf(float a, float b) {
  union { __hip_bfloat162 h; short2 s; } u;
  u.h = __float22bfloat162_rn(float2{a, b});
  return u.s;
}

__device__ __forceinline__ int pk2bf_i(float a, float b) {
  union { __hip_bfloat162 h; int i; } u;
  u.h = __float22bfloat162_rn(float2{a, b});
  return u.i;
}

// async global->LDS, 16B per lane; LDS dest = wave-uniform base + lane*16
__device__ __forceinline__ void gld16(const void* g, void* l) {
  __builtin_amdgcn_global_load_lds(
      (const __attribute__((address_space(1))) void*)g,
      (__attribute__((address_space(3))) void*)l, 16, 0, 0);
}

// Tile swizzle: stored chunk c of row r holds source chunk c^(r&7)^((r>>3)&3).
__device__ __forceinline__ int swz(int row, int col) {
  return (col ^ (row & 7) ^ ((row >> 3) & 3)) << 3;
}

// ---------------------------------------------------------------------------
// fp32 -> bf16 convert, weights only (q/k/v conversion fused into qkv_gemm)
// ---------------------------------------------------------------------------
struct CvtArgs {
  const float* s[4];
  short* d[4];
};

__global__ __launch_bounds__(256) void cvt_all(CvtArgs a) {
  const int y = blockIdx.y;
  const int i = blockIdx.x * 256 + threadIdx.x;  // 131072 chunks of 8
  const float4* sp = (const float4*)a.s[y];
  float4 u = sp[2 * i], v = sp[2 * i + 1];
  short8 o;
  short2 p0 = pk2bf(u.x, u.y), p1 = pk2bf(u.z, u.w);
  short2 p2 = pk2bf(v.x, v.y), p3 = pk2bf(v.z, v.w);
  o[0] = p0.x; o[1] = p0.y; o[2] = p1.x; o[3] = p1.y;
  o[4] = p2.x; o[5] = p2.y; o[6] = p3.x; o[7] = p3.y;
  ((short8*)a.d[y])[i] = o;
}

// ---------------------------------------------------------------------------
// Fused QKV projection GEMM, round-9: A staged as RAW FP32 via async
// gld16 (12 pure gld16/iter; zero sync loads), converted to bf16 at
// fragment-read time. Round-8's fragment read double-applied the lxor
// XOR to the A chunk index (stored-vs-source confusion; W path was
// correct) — fixed: esrc = 2c+half; A float4s at (2esrc)^lxor,
// (2esrc+1)^lxor; W offset (esrc^lxor)<<3. LDS 48 KB (A fp32 32K +
// W 16K), 3 blocks/CU, XCD-remapped. Numerics bit-identical to the
// old cvt+bf16 path.
// ---------------------------------------------------------------------------
struct QkvArgs {
  const float* A[3];   // fp32 inputs q,k,v
  const short* W[3];
  const float* b[3];
  short* out[3];
};

__global__ __launch_bounds__(256, 3) void qkv_gemm(QkvArgs args) {
  // bijective flat-id remap: xcd = f&7 (hardware round-robin assumption)
  const int f = blockIdx.x + 32 * (blockIdx.y + 8 * blockIdx.z);
  const int xcd = f & 7, slot = f >> 3;   // slot in [0,96)
  const int z = slot >> 5;                // which projection (q/k/v)
  const int rem = slot & 31;
  const int m0 = (xcd * 4 + (rem & 3)) * 128;  // s
  const int n0 = (rem >> 2) * 128;             // feat

  const float* __restrict__ A = args.A[z];
  const short* __restrict__ W = args.W[z];
  const float* __restrict__ bias = args.b[z];
  short* __restrict__ Cout = args.out[z];

  const int tid = threadIdx.x;
  const int wave = tid >> 6, lane = tid & 63;
  const int l32 = lane & 31, half = lane >> 5;
  const int wrow = (wave >> 1) * 64;
  const int wcol = (wave & 1) * 64;
  const int lxor = (l32 & 7) ^ ((l32 >> 3) & 3);

  __shared__ short smem[24576];                   // 48 KB total
  float* AmF = (float*)smem;                      // [128][64] fp32, swizzled
  short (*Wm)[64] = (short(*)[64])(smem + 16384); // [128][64] bf16, swizzled

  f32x16 acc[2][2];
#pragma unroll
  for (int mb = 0; mb < 2; mb++)
#pragma unroll
    for (int nb = 0; nb < 2; nb++) acc[mb][nb] = (f32x16)0.f;

  for (int k0 = 0; k0 < GK; k0 += 64) {
    __syncthreads();
    // A: 128 rows x 16 chunks(16B=4 fp32) = 2048 -> 8 gld16 per thread.
    // Stored chunk c16 of row r holds source chunk c16^(r&7)^((r>>3)&3).
#pragma unroll
    for (int i = 0; i < 8; i++) {
      int f2 = tid + i * 256;
      int r = f2 >> 4, c16 = f2 & 15;
      int csrc = c16 ^ (r & 7) ^ ((r >> 3) & 3);
      gld16(A + (size_t)(m0 + r) * GK + k0 + csrc * 4,
            AmF + (size_t)f2 * 4);
    }
    // W: 128 rows x 8 chunks(16B=8 bf16) = 1024 -> 4 gld16 per thread
#pragma unroll
    for (int i = 0; i < 4; i++) {
      int f2 = wave * 256 + i * 64 + lane;
      int row = f2 >> 3, col = f2 & 7;
      gld16(W + (size_t)(n0 + row) * GK + k0 + swz(row, col),
            (short*)Wm + (size_t)f2 * 8);
    }
    __syncthreads();
#pragma unroll
    for (int c = 0; c < 4; c++) {
      const int esrc = 2 * c + half;        // SOURCE 8-elem chunk index
      const int sw = (esrc ^ lxor) << 3;    // stored bf16 offset (W)
      short8 af[2], bf[2];
#pragma unroll
      for (int mb = 0; mb < 2; mb++) {
        // A: for these rows (row&7)^((row>>3)&3) == lxor, so source 16B
        // chunks 2esrc, 2esrc+1 live at stored slots (2esrc)^lxor, etc.
        const int row = wrow + mb * 32 + l32;
        const float4* base = (const float4*)AmF + row * 16;
        float4 a0 = base[(2 * esrc) ^ lxor];
        float4 a1 = base[(2 * esrc + 1) ^ lxor];
        short2 q0 = pk2bf(a0.x, a0.y), q1 = pk2bf(a0.z, a0.w);
        short2 q2 = pk2bf(a1.x, a1.y), q3 = pk2bf(a1.z, a1.w);
        af[mb][0] = q0.x; af[mb][1] = q0.y; af[mb][2] = q1.x; af[mb][3] = q1.y;
        af[mb][4] = q2.x; af[mb][5] = q2.y; af[mb][6] = q3.x; af[mb][7] = q3.y;
        bf[mb] = *(const short8*)(&Wm[wcol + mb * 32 + l32][0] + sw);
      }
#pragma unroll
      for (int mb = 0; mb < 2; mb++)
#pragma unroll
        for (int nb = 0; nb < 2; nb++)
          acc[mb][nb] = __builtin_amdgcn_mfma_f32_32x32x16_bf16(
              af[mb], bf[nb], acc[mb][nb], 0, 0, 0);
    }
  }

  const int bb = m0 >> 11;

  if (z == 2) {
    // --- V^T epilogue: transpose via LDS, coalesced stores ---
    __syncthreads();  // all K-loop LDS reads done before overwrite
    short* TT = smem; // [128 feat][16 chunks of 8 s], chunk-XOR swizzled
#pragma unroll
    for (int nb = 0; nb < 2; nb++) {
      const int fl = wcol + nb * 32 + l32;   // feat_local 0..127
      const float bv = bias[n0 + fl];
#pragma unroll
      for (int mb = 0; mb < 2; mb++)
#pragma unroll
        for (int g = 0; g < 4; g++) {
          const int cs = (wrow >> 3) + mb * 4 + g;            // 0..15
          const int csw = cs ^ (fl & 7) ^ ((fl >> 3) & 3);
          short2 o0 = pk2bf(acc[mb][nb][4 * g + 0] + bv,
                            acc[mb][nb][4 * g + 1] + bv);
          short2 o1 = pk2bf(acc[mb][nb][4 * g + 2] + bv,
                            acc[mb][nb][4 * g + 3] + bv);
          short4 o4 = {o0.x, o0.y, o1.x, o1.y};
          *(short4*)&TT[fl * 128 + csw * 8 + 4 * half] = o4;
        }
    }
    __syncthreads();
    {
      const int fl = tid >> 1;                       // feat row 0..127
      const int h = (n0 + fl) >> 6, d = (n0 + fl) & 63;
      short* dst = Cout + ((size_t)(bb * 16 + h) * 64 + d) * 2048 +
                   (m0 & 2047) + (tid & 1) * 64;
#pragma unroll
      for (int j = 0; j < 8; j++) {
        const int c8 = (tid & 1) * 8 + j;
        const int csw = c8 ^ (fl & 7) ^ ((fl >> 3) & 3);
        *(short8*)(dst + j * 8) = *(const short8*)&TT[fl * 128 + csw * 8];
      }
    }
    return;
  }

  // --- q/k epilogue: n(lane)=feat, m(regs)=s. Coalesced along feat. ---
  const float sc = (z == 0) ? QSCALE : 1.0f;
#pragma unroll
  for (int nb = 0; nb < 2; nb++) {
    const int n = n0 + wcol + nb * 32 + l32;
    const float bv = bias[n];
    const int h = n >> 6, d = n & 63;
#pragma unroll
    for (int mb = 0; mb < 2; mb++) {
      const int mbase = m0 + wrow + mb * 32 + 4 * half;
#pragma unroll
      for (int g = 0; g < 4; g++)
#pragma unroll
        for (int r = 0; r < 4; r++) {
          const int s = (mbase + g * 8 + r) & 2047;
          Cout[((size_t)(bb * 16 + h) * 2048 + s) * 64 + d] =
              f2bf((acc[mb][nb][4 * g + r] + bv) * sc);
        }
    }
  }
}

// ---------------------------------------------------------------------------
// O-projection GEMM, BK=128: 16 MFMA/wave/iter, 16 barriers. LDS 48 KB,
// grid (32,16) = 512 = 2 blocks/CU. fp32 out, coalesced along feat.
// XCD remap: each XCD owns 4 m-panels x all 16 n-tiles: A 1MB + W 2MB.
// ---------------------------------------------------------------------------
__global__ __launch_bounds__(256) void gemm_o(
    const short* __restrict__ A, const short* __restrict__ W,
    const float* __restrict__ bias, float* __restrict__ Cout) {
  const int f = blockIdx.x + 32 * blockIdx.y;
  const int xcd = f & 7, slot = f >> 3;        // slot in [0,64)
  const int m0 = (xcd * 4 + (slot & 3)) * 128; // s
  const int n0 = (slot >> 2) * 64;             // feat

  const int tid = threadIdx.x;
  const int wave = tid >> 6, lane = tid & 63;
  const int l32 = lane & 31, half = lane >> 5;
  const int lxor = (l32 & 7) ^ ((l32 >> 3) & 3);

  __shared__ short Am[128][128];  // [s][k], swizzled (32 KB)
  __shared__ short Wm[64][128];   // [feat][k], swizzled (16 KB)

  f32x16 acc[2];
  acc[0] = (f32x16)0.f;
  acc[1] = (f32x16)0.f;

  for (int k0 = 0; k0 < GK; k0 += 128) {
    __syncthreads();
    // A: 128 rows x 16 chunks = 2048 chunks -> 8 per thread
#pragma unroll
    for (int i = 0; i < 8; i++) {
      int f2 = tid + i * 256;
      int row = f2 >> 4, col = f2 & 15;
      gld16(A + (size_t)(m0 + row) * GK + k0 + swz(row, col),
            (short*)Am + (size_t)(wave * 64 + i * 256) * 8);
    }
    // W: 64 rows x 16 chunks = 1024 chunks -> 4 per thread
#pragma unroll
    for (int i = 0; i < 4; i++) {
      int f2 = tid + i * 256;
      int row = f2 >> 4, col = f2 & 15;
      gld16(W + (size_t)(n0 + row) * GK + k0 + swz(row, col),
            (short*)Wm + (size_t)(wave * 64 + i * 256) * 8);
    }
    __syncthreads();
#pragma unroll
    for (int c = 0; c < 8; c++) {
      const int sw = ((2 * c + half) ^ lxor) << 3;
      short8 af = *(const short8*)(&Am[wave * 32 + l32][0] + sw);
      short8 bf[2];
#pragma unroll
      for (int nb = 0; nb < 2; nb++)
        bf[nb] = *(const short8*)(&Wm[nb * 32 + l32][0] + sw);
#pragma unroll
      for (int nb = 0; nb < 2; nb++)
        acc[nb] = __builtin_amdgcn_mfma_f32_32x32x16_bf16(
            af, bf[nb], acc[nb], 0, 0, 0);
    }
  }

  // n(lane)=feat -> coalesced scalar stores
#pragma unroll
  for (int nb = 0; nb < 2; nb++) {
    const int n = n0 + nb * 32 + l32;
    const float bv = bias[n];
    const int mbase = m0 + wave * 32 + 4 * half;
#pragma unroll
    for (int g = 0; g < 4; g++)
#pragma unroll
      for (int r = 0; r < 4; r++)
        Cout[(size_t)(mbase + g * 8 + r) * DD + n] = acc[nb][4 * g + r] + bv;
  }
}

// ---------------------------------------------------------------------------
// Flash attention — round-7 schedule (kept): kt-split 8-wave blocks,
// in-register P, register-neutral intra-phase overlap, setprio, XCD remap.
// ---------------------------------------------------------------------------
__global__ __launch_bounds__(512, 4) void flash_mfma(
    const short* __restrict__ qh, const short* __restrict__ kh,
    const short* __restrict__ vt, short* __restrict__ ao) {
  // bijective remap: hardware flat id -> (bh, q-tile), 4 bh per XCD
  const int n = blockIdx.x + 16 * blockIdx.y;
  const int xcd = n & 7, slot = n >> 3;   // slot in [0,64)
  const int bh = xcd * 4 + (slot >> 4);
  const int q0 = (slot & 15) * 128;

  const int tid = threadIdx.x;
  const int w = tid >> 6, lane = tid & 63;
  const int grp = w >> 2;   // 0: even kt tiles, 1: odd kt tiles
  const int qw = w & 3;     // q sub-block (32 rows)
  const int l32 = lane & 31, half = lane >> 5;
  const int lxor = (l32 & 7) ^ ((l32 >> 3) & 3);

  __shared__ short Ks[4][64][64];   // 4 bufs x [kk][d], swizzled (32 KB)
  __shared__ short Vs[4][64][64];   // 4 bufs x [d][kk], swizzled (32 KB)

  // Q B-fragments from global: q = l32, chunk c: d = c*16 + half*8
  short8 qf[4];
#pragma unroll
  for (int c = 0; c < 4; c++)
    qf[c] = *(const short8*)(
        qh + ((size_t)bh * SS + q0 + qw * 32 + l32) * 64 + c * 16 + half * 8);

  f32x16 o[2];
  o[0] = (f32x16)0.f;
  o[1] = (f32x16)0.f;
  float l_part = 0.f;

  // Staging: thread owns chunk tid of each 64x64 tile (8 waves cover it).
  const int row = tid >> 3, col = tid & 7;
  const short* kb = kh + ((size_t)bh * SS + row) * 64 + swz(row, col);
  const short* vb = vt + ((size_t)bh * 64 + row) * SS + swz(row, col);
  short* kd = (short*)Ks + w * 512;   // wave-uniform LDS dest (+ buf*4096)
  short* vd = (short*)Vs + w * 512;

  // Prologue: tiles 0,1 -> bufs 0,1
  gld16(kb, kd);
  gld16(kb + 4096, kd + 4096);
  gld16(vb, vd);
  gld16(vb + 64, vd + 4096);
  const short* kp = kb + 8192;  // tile 2 (advances 2 tiles/phase)
  const short* vp = vb + 128;
  __syncthreads();

  auto phase = [&](const int bufbase, const bool pf) {
    if (pf) {  // prefetch next tile pair into the other buffer pair
      const int pb = bufbase ^ 2;
      gld16(kp, kd + pb * 4096);
      gld16(kp + 4096, kd + (pb + 1) * 4096);
      gld16(vp, vd + pb * 4096);
      gld16(vp + 64, vd + (pb + 1) * 4096);
      kp += 8192;
      vp += 128;
    }
    const int b = bufbase + grp;

    // S^T = K · Q^T : m = kk (2 blocks), n = q
    f32x16 s[2];
    s[0] = (f32x16)0.f;
    s[1] = (f32x16)0.f;
    __builtin_amdgcn_s_setprio(1);
#pragma unroll
    for (int c = 0; c < 4; c++) {
      const int sw = ((2 * c + half) ^ lxor) << 3;
      short8 kf[2];
#pragma unroll
      for (int mb = 0; mb < 2; mb++)
        kf[mb] = *(const short8*)(&Ks[b][mb * 32 + l32][0] + sw);
#pragma unroll
      for (int mb = 0; mb < 2; mb++)
        s[mb] = __builtin_amdgcn_mfma_f32_32x32x16_bf16(
            kf[mb], qf[c], s[mb], 0, 0, 0);
    }
    __builtin_amdgcn_s_setprio(0);

    short8 pfrag[4];

    // exp2 + pack for s[0] -> pfrag[0,1]
#pragma unroll
    for (int r = 0; r < 16; r++)
      s[0][r] = __builtin_amdgcn_exp2f(s[0][r]);
    {
      int u0[4], u1[4];
#pragma unroll
      for (int g = 0; g < 4; g++) {
        u0[g] = pk2bf_i(s[0][4 * g + 0], s[0][4 * g + 1]);
        u1[g] = pk2bf_i(s[0][4 * g + 2], s[0][4 * g + 3]);
      }
#pragma unroll
      for (int cc = 0; cc < 2; cc++) {
        auto r0 = __builtin_amdgcn_permlane32_swap(u0[2 * cc], u0[2 * cc + 1],
                                                   false, false);
        auto r1 = __builtin_amdgcn_permlane32_swap(u1[2 * cc], u1[2 * cc + 1],
                                                   false, false);
        union { i32x4 i; short8 s8; } pu;
        pu.i = i32x4{(int)r0[0], (int)r1[0], (int)r0[1], (int)r1[1]};
        pfrag[cc] = pu.s8;
      }
    }

    // PV c=0,1 (inline V reads; independent of s[1] -> exp2(s[1]) overlaps)
    __builtin_amdgcn_s_setprio(1);
#pragma unroll
    for (int c = 0; c < 2; c++) {
      const int sw = ((2 * c + half) ^ lxor) << 3;
      short8 vf[2];
#pragma unroll
      for (int mb = 0; mb < 2; mb++)
        vf[mb] = *(const short8*)(&Vs[b][mb * 32 + l32][0] + sw);
#pragma unroll
      for (int mb = 0; mb < 2; mb++)
        o[mb] = __builtin_amdgcn_mfma_f32_32x32x16_bf16(
            vf[mb], pfrag[c], o[mb], 0, 0, 0);
    }
    __builtin_amdgcn_s_setprio(0);

    // exp2 + pack for s[1] -> pfrag[2,3] (under PV c=0,1's shadow)
#pragma unroll
    for (int r = 0; r < 16; r++)
      s[1][r] = __builtin_amdgcn_exp2f(s[1][r]);
    {
      int u0[4], u1[4];
#pragma unroll
      for (int g = 0; g < 4; g++) {
        u0[g] = pk2bf_i(s[1][4 * g + 0], s[1][4 * g + 1]);
        u1[g] = pk2bf_i(s[1][4 * g + 2], s[1][4 * g + 3]);
      }
#pragma unroll
      for (int cc = 0; cc < 2; cc++) {
        auto r0 = __builtin_amdgcn_permlane32_swap(u0[2 * cc], u0[2 * cc + 1],
                                                   false, false);
        auto r1 = __builtin_amdgcn_permlane32_swap(u1[2 * cc], u1[2 * cc + 1],
                                                   false, false);
        union { i32x4 i; short8 s8; } pu;
        pu.i = i32x4{(int)r0[0], (int)r1[0], (int)r0[1], (int)r1[1]};
        pfrag[2 + cc] = pu.s8;
      }
    }

    // PV c=2,3
    __builtin_amdgcn_s_setprio(1);
#pragma unroll
    for (int c = 2; c < 4; c++) {
      const int sw = ((2 * c + half) ^ lxor) << 3;
      short8 vf[2];
#pragma unroll
      for (int mb = 0; mb < 2; mb++)
        vf[mb] = *(const short8*)(&Vs[b][mb * 32 + l32][0] + sw);
#pragma unroll
      for (int mb = 0; mb < 2; mb++)
        o[mb] = __builtin_amdgcn_mfma_f32_32x32x16_bf16(
            vf[mb], pfrag[c], o[mb], 0, 0, 0);
    }
    __builtin_amdgcn_s_setprio(0);

    // per-lane partial l (VALU; runs under PV c=2,3's matrix-pipe shadow)
    {
      f32x2 t[8];
#pragma unroll
      for (int r = 0; r < 8; r++)
        t[r] = f32x2{s[0][2 * r], s[0][2 * r + 1]} +
               f32x2{s[1][2 * r], s[1][2 * r + 1]};
#pragma unroll
      for (int st = 4; st > 0; st >>= 1)
#pragma unroll
        for (int r = 0; r < st; r++) t[r] += t[r + st];
      l_part += t[0].x + t[0].y;
    }

    __syncthreads();  // drains prefetch + guards buffer reuse
  };

#pragma unroll 1
  for (int p2 = 0; p2 < 8; p2++) {
    phase(0, true);       // tiles 4*p2, 4*p2+1 (bufs 0,1); stage bufs 2,3
    phase(2, p2 != 7);    // tiles 4*p2+2,+3  (bufs 2,3); stage bufs 0,1
  }

  // Epilogue: merge group-1 partials into group-0 via LDS, then store.
  float* fb = (float*)Ks;  // 32*256 f32 = 32 KB
  float* lb = (float*)Vs;
  if (grp == 1) {
#pragma unroll
    for (int mb = 0; mb < 2; mb++)
#pragma unroll
      for (int r = 0; r < 16; r++)
        fb[(mb * 16 + r) * 256 + qw * 64 + lane] = o[mb][r];
    lb[qw * 64 + lane] = l_part;
  }
  __syncthreads();
  if (grp == 0) {
#pragma unroll
    for (int mb = 0; mb < 2; mb++)
#pragma unroll
      for (int r = 0; r < 16; r++)
        o[mb][r] += fb[(mb * 16 + r) * 256 + qw * 64 + lane];
    l_part += lb[qw * 64 + lane];

    const float l_tot = l_part + __shfl_xor(l_part, 32);
    const float inv = 1.0f / l_tot;
    const int b_ = bh >> 4, h = bh & 15;
    const int q = q0 + qw * 32 + l32;
#pragma unroll
    for (int mb = 0; mb < 2; mb++)
#pragma unroll
      for (int g = 0; g < 4; g++) {
        const int d = mb * 32 + g * 8 + half * 4;
        short2 o0 = pk2bf(o[mb][4 * g + 0] * inv, o[mb][4 * g + 1] * inv);
        short2 o1 = pk2bf(o[mb][4 * g + 2] * inv, o[mb][4 * g + 3] * inv);
        short4 ok = {o0.x, o0.y, o1.x, o1.y};
        *(short4*)&ao[((size_t)b_ * SS + q) * DD + h * 64 + d] = ok;
      }
  }
}

// ---------------------------------------------------------------------------
extern "C" void kernel_launch(void* const* d_in, const int* in_sizes, int n_in,
                              void* d_out, int out_size, void* d_ws,
                              size_t ws_size, hipStream_t stream) {
  const float* q = (const float*)d_in[0];
  const float* k = (const float*)d_in[1];
  const float* v = (const float*)d_in[2];
  const float* Wq = (const float*)d_in[3];
  const float* bq = (const float*)d_in[4];
  const float* Wk = (const float*)d_in[5];
  const float* bk = (const float*)d_in[6];
  const float* Wv = (const float*)d_in[7];
  const float* bv = (const float*)d_in[8];
  const float* Wo = (const float*)d_in[9];
  const float* bo = (const float*)d_in[10];
  float* out = (float*)d_out;

  const size_t MEG = 1024 * 1024;
  short* wsb = (short*)d_ws;
  short* Wqb = wsb + 0 * MEG;
  short* Wkb = wsb + 1 * MEG;
  short* Wvb = wsb + 2 * MEG;
  short* Wob = wsb + 3 * MEG;
  short* qhp = wsb + 16 * MEG;  // [B*H][S][DH] (pre-scaled by log2e/8)
  short* khp = wsb + 20 * MEG;  // [B*H][S][DH]
  short* vtp = wsb + 24 * MEG;  // [B*H][DH][S]
  short* aop = wsb + 28 * MEG;  // [B,S,D]

  CvtArgs ca;
  ca.s[0] = Wq; ca.d[0] = Wqb;
  ca.s[1] = Wk; ca.d[1] = Wkb;
  ca.s[2] = Wv; ca.d[2] = Wvb;
  ca.s[3] = Wo; ca.d[3] = Wob;
  cvt_all<<<dim3(512, 4), 256, 0, stream>>>(ca);

  QkvArgs qa;
  qa.A[0] = q; qa.W[0] = Wqb; qa.b[0] = bq; qa.out[0] = qhp;
  qa.A[1] = k; qa.W[1] = Wkb; qa.b[1] = bk; qa.out[1] = khp;
  qa.A[2] = v; qa.W[2] = Wvb; qa.b[2] = bv; qa.out[2] = vtp;
  qkv_gemm<<<dim3(GM / 128, DD / 128, 3), 256, 0, stream>>>(qa);

  flash_mfma<<<dim3(SS / 128, 32), 512, 0, stream>>>(qhp, khp, vtp, aop);

  gemm_o<<<dim3(GM / 128, DD / 64), 256, 0, stream>>>(aop, Wob, bo, out);
}

// Round 10
// 205.583 us; speedup vs baseline: 1.0570x; 1.0279x over previous
//
#include <hip/hip_runtime.h>
#include <hip/hip_bf16.h>

// Problem constants: B=2, S=2048, D=1024, H=16, DH=64
#define SS 2048
#define DD 1024
#define GK 1024   // GEMM K = D
#define GM 4096   // GEMM M = B*S

// log2(e)/8 : folded into Q projection so attention softmax is exp2(s)
#define QSCALE 0.18033688011112042f

typedef __attribute__((ext_vector_type(8))) short short8;    // 8 bf16 = 4 VGPRs
typedef __attribute__((ext_vector_type(16))) float f32x16;   // 32x32 MFMA C/D
typedef __attribute__((ext_vector_type(2))) float f32x2;
typedef __attribute__((ext_vector_type(4))) int i32x4;

__device__ __forceinline__ short f2bf(float f) {
  union { __hip_bfloat16 h; short s; } u;
  u.h = __float2bfloat16(f);
  return u.s;
}

__device__ __forceinline__ short2 pk2bf(float a, float b) {
  union { __hip_bfloat162 h; short2 s; } u;
  u.h = __float22bfloat162_rn(float2{a, b});
  return u.s;
}

__device__ __forceinline__ int pk2bf_i(float a, float b) {
  union { __hip_bfloat162 h; int i; } u;
  u.h = __float22bfloat162_rn(float2{a, b});
  return u.i;
}

// async global->LDS, 16B per lane; LDS dest = wave-uniform base + lane*16
__device__ __forceinline__ void gld16(const void* g, void* l) {
  __builtin_amdgcn_global_load_lds(
      (const __attribute__((address_space(1))) void*)g,
      (__attribute__((address_space(3))) void*)l, 16, 0, 0);
}

// Tile swizzle: stored chunk c of row r holds source chunk c^(r&7)^((r>>3)&3).
__device__ __forceinline__ int swz(int row, int col) {
  return (col ^ (row & 7) ^ ((row >> 3) & 3)) << 3;
}

// ---------------------------------------------------------------------------
// Fused fp32 -> bf16 convert for 7 arrays (q,k,v + 4 weights)
// ---------------------------------------------------------------------------
struct CvtArgs {
  const float* s[7];
  short* d[7];
  int n8[7];
};

__global__ __launch_bounds__(256) void cvt_all(CvtArgs a) {
  const int y = blockIdx.y;
  const int i = blockIdx.x * 256 + threadIdx.x;
  if (i >= a.n8[y]) return;
  const float4* sp = (const float4*)a.s[y];
  float4 u = sp[2 * i], v = sp[2 * i + 1];
  short8 o;
  short2 p0 = pk2bf(u.x, u.y), p1 = pk2bf(u.z, u.w);
  short2 p2 = pk2bf(v.x, v.y), p3 = pk2bf(v.z, v.w);
  o[0] = p0.x; o[1] = p0.y; o[2] = p1.x; o[3] = p1.y;
  o[4] = p2.x; o[5] = p2.y; o[6] = p3.x; o[7] = p3.y;
  ((short8*)a.d[y])[i] = o;
}

// ---------------------------------------------------------------------------
// Fused QKV projection GEMM, round-10: 2-PHASE double-buffered schedule.
// Previous structure (all 4 variants tried, all ~55us): barrier -> STAGE(t)
// -> barrier -> compute(t). The pre-barrier vmcnt(0) drain exposes the
// full load latency of tile t right after issue, every k-step (MfmaUtil =
// VALU = HBM = 16%, all idle). Now: STAGE(t+1) issues BEFORE compute(t),
// ONE barrier per step; the end-of-step drain covers loads that had the
// whole 16-MFMA phase in flight (catalog T3-min: 2ph ~= 92% of 8ph).
// A back to bf16 (cvt pass) so Am[2]+Wm[2] = 64 KB -> 2 blocks/CU.
// Staging/fragment index code identical to the round-2 passing kernel.
// ---------------------------------------------------------------------------
struct QkvArgs {
  const short* A[3];   // bf16 inputs qb,kb,vb
  const short* W[3];
  const float* b[3];
  short* out[3];
};

__global__ __launch_bounds__(256, 2) void qkv_gemm(QkvArgs args) {
  // bijective flat-id remap: xcd = f&7 (hardware round-robin assumption)
  const int f = blockIdx.x + 32 * (blockIdx.y + 8 * blockIdx.z);
  const int xcd = f & 7, slot = f >> 3;   // slot in [0,96)
  const int z = slot >> 5;                // which projection (q/k/v)
  const int rem = slot & 31;
  const int m0 = (xcd * 4 + (rem & 3)) * 128;  // s
  const int n0 = (rem >> 2) * 128;             // feat

  const short* __restrict__ A = args.A[z];
  const short* __restrict__ W = args.W[z];
  const float* __restrict__ bias = args.b[z];
  short* __restrict__ Cout = args.out[z];

  const int tid = threadIdx.x;
  const int wave = tid >> 6, lane = tid & 63;
  const int l32 = lane & 31, half = lane >> 5;
  const int wrow = (wave >> 1) * 64;
  const int wcol = (wave & 1) * 64;
  const int lxor = (l32 & 7) ^ ((l32 >> 3) & 3);

  __shared__ short smem[32768];   // 64 KB: Am[2] (16K ea) | Wm[2] (16K ea)
  // buf b: A at smem + b*8192, W at smem + 16384 + b*8192  (shorts)

  f32x16 acc[2][2];
#pragma unroll
  for (int mb = 0; mb < 2; mb++)
#pragma unroll
    for (int nb = 0; nb < 2; nb++) acc[mb][nb] = (f32x16)0.f;

  // ---- stage tile t into buffer buf (round-2 index code, dbuf base) ----
  auto stage = [&](int k0, int buf) {
    short* Ab = smem + buf * 8192;
    short* Wb = smem + 16384 + buf * 8192;
#pragma unroll
    for (int i = 0; i < 4; i++) {
      int f2 = wave * 256 + i * 64 + lane;
      int row = f2 >> 3, col = f2 & 7;
      int ksw = k0 + swz(row, col);
      gld16(A + (size_t)(m0 + row) * GK + ksw,
            Ab + (size_t)(wave * 256 + i * 64) * 8);
      gld16(W + (size_t)(n0 + row) * GK + ksw,
            Wb + (size_t)(wave * 256 + i * 64) * 8);
    }
  };

  // Prologue: tile 0 -> buf 0
  stage(0, 0);
  __syncthreads();

  for (int t = 0; t < 16; t++) {
    if (t < 15) stage((t + 1) * 64, (t + 1) & 1);   // overlaps compute(t)
    const short* Ab = smem + (t & 1) * 8192;
    const short* Wb = smem + 16384 + (t & 1) * 8192;
#pragma unroll
    for (int c = 0; c < 4; c++) {
      const int sw = ((2 * c + half) ^ lxor) << 3;
      short8 af[2], bf[2];
#pragma unroll
      for (int mb = 0; mb < 2; mb++) {
        af[mb] = *(const short8*)(Ab + (wrow + mb * 32 + l32) * 64 + sw);
        bf[mb] = *(const short8*)(Wb + (wcol + mb * 32 + l32) * 64 + sw);
      }
#pragma unroll
      for (int mb = 0; mb < 2; mb++)
#pragma unroll
        for (int nb = 0; nb < 2; nb++)
          acc[mb][nb] = __builtin_amdgcn_mfma_f32_32x32x16_bf16(
              af[mb], bf[nb], acc[mb][nb], 0, 0, 0);
    }
    __syncthreads();  // drains stage(t+1); guards buf[t&1] for overwrite
  }

  const int bb = m0 >> 11;

  if (z == 2) {
    // --- V^T epilogue: transpose via LDS (first 32 KB), coalesced stores ---
    short* TT = smem; // [128 feat][16 chunks of 8 s], chunk-XOR swizzled
#pragma unroll
    for (int nb = 0; nb < 2; nb++) {
      const int fl = wcol + nb * 32 + l32;   // feat_local 0..127
      const float bv = bias[n0 + fl];
#pragma unroll
      for (int mb = 0; mb < 2; mb++)
#pragma unroll
        for (int g = 0; g < 4; g++) {
          const int cs = (wrow >> 3) + mb * 4 + g;            // 0..15
          const int csw = cs ^ (fl & 7) ^ ((fl >> 3) & 3);
          short2 o0 = pk2bf(acc[mb][nb][4 * g + 0] + bv,
                            acc[mb][nb][4 * g + 1] + bv);
          short2 o1 = pk2bf(acc[mb][nb][4 * g + 2] + bv,
                            acc[mb][nb][4 * g + 3] + bv);
          short4 o4 = {o0.x, o0.y, o1.x, o1.y};
          *(short4*)&TT[fl * 128 + csw * 8 + 4 * half] = o4;
        }
    }
    __syncthreads();
    {
      const int fl = tid >> 1;                       // feat row 0..127
      const int h = (n0 + fl) >> 6, d = (n0 + fl) & 63;
      short* dst = Cout + ((size_t)(bb * 16 + h) * 64 + d) * 2048 +
                   (m0 & 2047) + (tid & 1) * 64;
#pragma unroll
      for (int j = 0; j < 8; j++) {
        const int c8 = (tid & 1) * 8 + j;
        const int csw = c8 ^ (fl & 7) ^ ((fl >> 3) & 3);
        *(short8*)(dst + j * 8) = *(const short8*)&TT[fl * 128 + csw * 8];
      }
    }
    return;
  }

  // --- q/k epilogue: n(lane)=feat, m(regs)=s. Coalesced along feat. ---
  const float sc = (z == 0) ? QSCALE : 1.0f;
#pragma unroll
  for (int nb = 0; nb < 2; nb++) {
    const int n = n0 + wcol + nb * 32 + l32;
    const float bv = bias[n];
    const int h = n >> 6, d = n & 63;
#pragma unroll
    for (int mb = 0; mb < 2; mb++) {
      const int mbase = m0 + wrow + mb * 32 + 4 * half;
#pragma unroll
      for (int g = 0; g < 4; g++)
#pragma unroll
        for (int r = 0; r < 4; r++) {
          const int s = (mbase + g * 8 + r) & 2047;
          Cout[((size_t)(bb * 16 + h) * 2048 + s) * 64 + d] =
              f2bf((acc[mb][nb][4 * g + r] + bv) * sc);
        }
    }
  }
}

// ---------------------------------------------------------------------------
// O-projection GEMM, BK=128: 16 MFMA/wave/iter, 16 barriers. LDS 48 KB,
// grid (32,16) = 512 = 2 blocks/CU. fp32 out, coalesced along feat.
// XCD remap: each XCD owns 4 m-panels x all 16 n-tiles: A 1MB + W 2MB.
// ---------------------------------------------------------------------------
__global__ __launch_bounds__(256) void gemm_o(
    const short* __restrict__ A, const short* __restrict__ W,
    const float* __restrict__ bias, float* __restrict__ Cout) {
  const int f = blockIdx.x + 32 * blockIdx.y;
  const int xcd = f & 7, slot = f >> 3;        // slot in [0,64)
  const int m0 = (xcd * 4 + (slot & 3)) * 128; // s
  const int n0 = (slot >> 2) * 64;             // feat

  const int tid = threadIdx.x;
  const int wave = tid >> 6, lane = tid & 63;
  const int l32 = lane & 31, half = lane >> 5;
  const int lxor = (l32 & 7) ^ ((l32 >> 3) & 3);

  __shared__ short Am[128][128];  // [s][k], swizzled (32 KB)
  __shared__ short Wm[64][128];   // [feat][k], swizzled (16 KB)

  f32x16 acc[2];
  acc[0] = (f32x16)0.f;
  acc[1] = (f32x16)0.f;

  for (int k0 = 0; k0 < GK; k0 += 128) {
    __syncthreads();
    // A: 128 rows x 16 chunks = 2048 chunks -> 8 per thread
#pragma unroll
    for (int i = 0; i < 8; i++) {
      int f2 = tid + i * 256;
      int row = f2 >> 4, col = f2 & 15;
      gld16(A + (size_t)(m0 + row) * GK + k0 + swz(row, col),
            (short*)Am + (size_t)(wave * 64 + i * 256) * 8);
    }
    // W: 64 rows x 16 chunks = 1024 chunks -> 4 per thread
#pragma unroll
    for (int i = 0; i < 4; i++) {
      int f2 = tid + i * 256;
      int row = f2 >> 4, col = f2 & 15;
      gld16(W + (size_t)(n0 + row) * GK + k0 + swz(row, col),
            (short*)Wm + (size_t)(wave * 64 + i * 256) * 8);
    }
    __syncthreads();
#pragma unroll
    for (int c = 0; c < 8; c++) {
      const int sw = ((2 * c + half) ^ lxor) << 3;
      short8 af = *(const short8*)(&Am[wave * 32 + l32][0] + sw);
      short8 bf[2];
#pragma unroll
      for (int nb = 0; nb < 2; nb++)
        bf[nb] = *(const short8*)(&Wm[nb * 32 + l32][0] + sw);
#pragma unroll
      for (int nb = 0; nb < 2; nb++)
        acc[nb] = __builtin_amdgcn_mfma_f32_32x32x16_bf16(
            af, bf[nb], acc[nb], 0, 0, 0);
    }
  }

  // n(lane)=feat -> coalesced scalar stores
#pragma unroll
  for (int nb = 0; nb < 2; nb++) {
    const int n = n0 + nb * 32 + l32;
    const float bv = bias[n];
    const int mbase = m0 + wave * 32 + 4 * half;
#pragma unroll
    for (int g = 0; g < 4; g++)
#pragma unroll
      for (int r = 0; r < 4; r++)
        Cout[(size_t)(mbase + g * 8 + r) * DD + n] = acc[nb][4 * g + r] + bv;
  }
}

// ---------------------------------------------------------------------------
// Flash attention — round-7 schedule (kept): kt-split 8-wave blocks,
// in-register P, register-neutral intra-phase overlap, setprio, XCD remap.
// ---------------------------------------------------------------------------
__global__ __launch_bounds__(512, 4) void flash_mfma(
    const short* __restrict__ qh, const short* __restrict__ kh,
    const short* __restrict__ vt, short* __restrict__ ao) {
  // bijective remap: hardware flat id -> (bh, q-tile), 4 bh per XCD
  const int n = blockIdx.x + 16 * blockIdx.y;
  const int xcd = n & 7, slot = n >> 3;   // slot in [0,64)
  const int bh = xcd * 4 + (slot >> 4);
  const int q0 = (slot & 15) * 128;

  const int tid = threadIdx.x;
  const int w = tid >> 6, lane = tid & 63;
  const int grp = w >> 2;   // 0: even kt tiles, 1: odd kt tiles
  const int qw = w & 3;     // q sub-block (32 rows)
  const int l32 = lane & 31, half = lane >> 5;
  const int lxor = (l32 & 7) ^ ((l32 >> 3) & 3);

  __shared__ short Ks[4][64][64];   // 4 bufs x [kk][d], swizzled (32 KB)
  __shared__ short Vs[4][64][64];   // 4 bufs x [d][kk], swizzled (32 KB)

  // Q B-fragments from global: q = l32, chunk c: d = c*16 + half*8
  short8 qf[4];
#pragma unroll
  for (int c = 0; c < 4; c++)
    qf[c] = *(const short8*)(
        qh + ((size_t)bh * SS + q0 + qw * 32 + l32) * 64 + c * 16 + half * 8);

  f32x16 o[2];
  o[0] = (f32x16)0.f;
  o[1] = (f32x16)0.f;
  float l_part = 0.f;

  // Staging: thread owns chunk tid of each 64x64 tile (8 waves cover it).
  const int row = tid >> 3, col = tid & 7;
  const short* kb = kh + ((size_t)bh * SS + row) * 64 + swz(row, col);
  const short* vb = vt + ((size_t)bh * 64 + row) * SS + swz(row, col);
  short* kd = (short*)Ks + w * 512;   // wave-uniform LDS dest (+ buf*4096)
  short* vd = (short*)Vs + w * 512;

  // Prologue: tiles 0,1 -> bufs 0,1
  gld16(kb, kd);
  gld16(kb + 4096, kd + 4096);
  gld16(vb, vd);
  gld16(vb + 64, vd + 4096);
  const short* kp = kb + 8192;  // tile 2 (advances 2 tiles/phase)
  const short* vp = vb + 128;
  __syncthreads();

  auto phase = [&](const int bufbase, const bool pf) {
    if (pf) {  // prefetch next tile pair into the other buffer pair
      const int pb = bufbase ^ 2;
      gld16(kp, kd + pb * 4096);
      gld16(kp + 4096, kd + (pb + 1) * 4096);
      gld16(vp, vd + pb * 4096);
      gld16(vp + 64, vd + (pb + 1) * 4096);
      kp += 8192;
      vp += 128;
    }
    const int b = bufbase + grp;

    // S^T = K · Q^T : m = kk (2 blocks), n = q
    f32x16 s[2];
    s[0] = (f32x16)0.f;
    s[1] = (f32x16)0.f;
    __builtin_amdgcn_s_setprio(1);
#pragma unroll
    for (int c = 0; c < 4; c++) {
      const int sw = ((2 * c + half) ^ lxor) << 3;
      short8 kf[2];
#pragma unroll
      for (int mb = 0; mb < 2; mb++)
        kf[mb] = *(const short8*)(&Ks[b][mb * 32 + l32][0] + sw);
#pragma unroll
      for (int mb = 0; mb < 2; mb++)
        s[mb] = __builtin_amdgcn_mfma_f32_32x32x16_bf16(
            kf[mb], qf[c], s[mb], 0, 0, 0);
    }
    __builtin_amdgcn_s_setprio(0);

    short8 pfrag[4];

    // exp2 + pack for s[0] -> pfrag[0,1]
#pragma unroll
    for (int r = 0; r < 16; r++)
      s[0][r] = __builtin_amdgcn_exp2f(s[0][r]);
    {
      int u0[4], u1[4];
#pragma unroll
      for (int g = 0; g < 4; g++) {
        u0[g] = pk2bf_i(s[0][4 * g + 0], s[0][4 * g + 1]);
        u1[g] = pk2bf_i(s[0][4 * g + 2], s[0][4 * g + 3]);
      }
#pragma unroll
      for (int cc = 0; cc < 2; cc++) {
        auto r0 = __builtin_amdgcn_permlane32_swap(u0[2 * cc], u0[2 * cc + 1],
                                                   false, false);
        auto r1 = __builtin_amdgcn_permlane32_swap(u1[2 * cc], u1[2 * cc + 1],
                                                   false, false);
        union { i32x4 i; short8 s8; } pu;
        pu.i = i32x4{(int)r0[0], (int)r1[0], (int)r0[1], (int)r1[1]};
        pfrag[cc] = pu.s8;
      }
    }

    // PV c=0,1 (inline V reads; independent of s[1] -> exp2(s[1]) overlaps)
    __builtin_amdgcn_s_setprio(1);
#pragma unroll
    for (int c = 0; c < 2; c++) {
      const int sw = ((2 * c + half) ^ lxor) << 3;
      short8 vf[2];
#pragma unroll
      for (int mb = 0; mb < 2; mb++)
        vf[mb] = *(const short8*)(&Vs[b][mb * 32 + l32][0] + sw);
#pragma unroll
      for (int mb = 0; mb < 2; mb++)
        o[mb] = __builtin_amdgcn_mfma_f32_32x32x16_bf16(
            vf[mb], pfrag[c], o[mb], 0, 0, 0);
    }
    __builtin_amdgcn_s_setprio(0);

    // exp2 + pack for s[1] -> pfrag[2,3] (under PV c=0,1's shadow)
#pragma unroll
    for (int r = 0; r < 16; r++)
      s[1][r] = __builtin_amdgcn_exp2f(s[1][r]);
    {
      int u0[4], u1[4];
#pragma unroll
      for (int g = 0; g < 4; g++) {
        u0[g] = pk2bf_i(s[1][4 * g + 0], s[1][4 * g + 1]);
        u1[g] = pk2bf_i(s[1][4 * g + 2], s[1][4 * g + 3]);
      }
#pragma unroll
      for (int cc = 0; cc < 2; cc++) {
        auto r0 = __builtin_amdgcn_permlane32_swap(u0[2 * cc], u0[2 * cc + 1],
                                                   false, false);
        auto r1 = __builtin_amdgcn_permlane32_swap(u1[2 * cc], u1[2 * cc + 1],
                                                   false, false);
        union { i32x4 i; short8 s8; } pu;
        pu.i = i32x4{(int)r0[0], (int)r1[0], (int)r0[1], (int)r1[1]};
        pfrag[2 + cc] = pu.s8;
      }
    }

    // PV c=2,3
    __builtin_amdgcn_s_setprio(1);
#pragma unroll
    for (int c = 2; c < 4; c++) {
      const int sw = ((2 * c + half) ^ lxor) << 3;
      short8 vf[2];
#pragma unroll
      for (int mb = 0; mb < 2; mb++)
        vf[mb] = *(const short8*)(&Vs[b][mb * 32 + l32][0] + sw);
#pragma unroll
      for (int mb = 0; mb < 2; mb++)
        o[mb] = __builtin_amdgcn_mfma_f32_32x32x16_bf16(
            vf[mb], pfrag[c], o[mb], 0, 0, 0);
    }
    __builtin_amdgcn_s_setprio(0);

    // per-lane partial l (VALU; runs under PV c=2,3's matrix-pipe shadow)
    {
      f32x2 t[8];
#pragma unroll
      for (int r = 0; r < 8; r++)
        t[r] = f32x2{s[0][2 * r], s[0][2 * r + 1]} +
               f32x2{s[1][2 * r], s[1][2 * r + 1]};
#pragma unroll
      for (int st = 4; st > 0; st >>= 1)
#pragma unroll
        for (int r = 0; r < st; r++) t[r] += t[r + st];
      l_part += t[0].x + t[0].y;
    }

    __syncthreads();  // drains prefetch + guards buffer reuse
  };

#pragma unroll 1
  for (int p2 = 0; p2 < 8; p2++) {
    phase(0, true);       // tiles 4*p2, 4*p2+1 (bufs 0,1); stage bufs 2,3
    phase(2, p2 != 7);    // tiles 4*p2+2,+3  (bufs 2,3); stage bufs 0,1
  }

  // Epilogue: merge group-1 partials into group-0 via LDS, then store.
  float* fb = (float*)Ks;  // 32*256 f32 = 32 KB
  float* lb = (float*)Vs;
  if (grp == 1) {
#pragma unroll
    for (int mb = 0; mb < 2; mb++)
#pragma unroll
      for (int r = 0; r < 16; r++)
        fb[(mb * 16 + r) * 256 + qw * 64 + lane] = o[mb][r];
    lb[qw * 64 + lane] = l_part;
  }
  __syncthreads();
  if (grp == 0) {
#pragma unroll
    for (int mb = 0; mb < 2; mb++)
#pragma unroll
      for (int r = 0; r < 16; r++)
        o[mb][r] += fb[(mb * 16 + r) * 256 + qw * 64 + lane];
    l_part += lb[qw * 64 + lane];

    const float l_tot = l_part + __shfl_xor(l_part, 32);
    const float inv = 1.0f / l_tot;
    const int b_ = bh >> 4, h = bh & 15;
    const int q = q0 + qw * 32 + l32;
#pragma unroll
    for (int mb = 0; mb < 2; mb++)
#pragma unroll
      for (int g = 0; g < 4; g++) {
        const int d = mb * 32 + g * 8 + half * 4;
        short2 o0 = pk2bf(o[mb][4 * g + 0] * inv, o[mb][4 * g + 1] * inv);
        short2 o1 = pk2bf(o[mb][4 * g + 2] * inv, o[mb][4 * g + 3] * inv);
        short4 ok = {o0.x, o0.y, o1.x, o1.y};
        *(short4*)&ao[((size_t)b_ * SS + q) * DD + h * 64 + d] = ok;
      }
  }
}

// ---------------------------------------------------------------------------
extern "C" void kernel_launch(void* const* d_in, const int* in_sizes, int n_in,
                              void* d_out, int out_size, void* d_ws,
                              size_t ws_size, hipStream_t stream) {
  const float* q = (const float*)d_in[0];
  const float* k = (const float*)d_in[1];
  const float* v = (const float*)d_in[2];
  const float* Wq = (const float*)d_in[3];
  const float* bq = (const float*)d_in[4];
  const float* Wk = (const float*)d_in[5];
  const float* bk = (const float*)d_in[6];
  const float* Wv = (const float*)d_in[7];
  const float* bv = (const float*)d_in[8];
  const float* Wo = (const float*)d_in[9];
  const float* bo = (const float*)d_in[10];
  float* out = (float*)d_out;

  const size_t MEG = 1024 * 1024;
  short* wsb = (short*)d_ws;
  short* Wqb = wsb + 0 * MEG;
  short* Wkb = wsb + 1 * MEG;
  short* Wvb = wsb + 2 * MEG;
  short* Wob = wsb + 3 * MEG;
  short* qb = wsb + 4 * MEG;    // bf16 copies of q,k,v: 4M shorts each
  short* kb = wsb + 8 * MEG;
  short* vb = wsb + 12 * MEG;
  short* qhp = wsb + 16 * MEG;  // [B*H][S][DH] (pre-scaled by log2e/8)
  short* khp = wsb + 20 * MEG;  // [B*H][S][DH]
  short* vtp = wsb + 24 * MEG;  // [B*H][DH][S]
  short* aop = wsb + 28 * MEG;  // [B,S,D]

  CvtArgs ca;
  ca.s[0] = q;  ca.d[0] = qb;  ca.n8[0] = 524288;
  ca.s[1] = k;  ca.d[1] = kb;  ca.n8[1] = 524288;
  ca.s[2] = v;  ca.d[2] = vb;  ca.n8[2] = 524288;
  ca.s[3] = Wq; ca.d[3] = Wqb; ca.n8[3] = 131072;
  ca.s[4] = Wk; ca.d[4] = Wkb; ca.n8[4] = 131072;
  ca.s[5] = Wv; ca.d[5] = Wvb; ca.n8[5] = 131072;
  ca.s[6] = Wo; ca.d[6] = Wob; ca.n8[6] = 131072;
  cvt_all<<<dim3(2048, 7), 256, 0, stream>>>(ca);

  QkvArgs qa;
  qa.A[0] = qb; qa.W[0] = Wqb; qa.b[0] = bq; qa.out[0] = qhp;
  qa.A[1] = kb; qa.W[1] = Wkb; qa.b[1] = bk; qa.out[1] = khp;
  qa.A[2] = vb; qa.W[2] = Wvb; qa.b[2] = bv; qa.out[2] = vtp;
  qkv_gemm<<<dim3(GM / 128, DD / 128, 3), 256, 0, stream>>>(qa);

  flash_mfma<<<dim3(SS / 128, 32), 512, 0, stream>>>(qhp, khp, vtp, aop);

  gemm_o<<<dim3(GM / 128, DD / 64), 256, 0, stream>>>(aop, Wob, bo, out);
}